// Round 9
// baseline (76.021 us; speedup 1.0000x reference)
//
#include <hip/hip_runtime.h>
#include <hip/hip_fp16.h>
#include <stdint.h>

// ---------------- problem constants ----------------
#define T_DIM   16384       // S*B tokens
#define LN_EPS  1e-5f

typedef _Float16 f16;
typedef __attribute__((ext_vector_type(2))) _Float16 h2v;
typedef __attribute__((ext_vector_type(4))) _Float16 h4v;
typedef __attribute__((ext_vector_type(8))) _Float16 h8v;
typedef __attribute__((ext_vector_type(4))) float    f32x4;

union H2U { uint32_t u; h2v h; };
union H8U { uint32_t u[4]; h8v v; };
union H8S { h8v v; uint16_t s[8]; };

// ============================================================
// Kernel 0: zero d_out (atomicAdd accumulation base). 2048 x 256 x 16B.
// ============================================================
__global__ __launch_bounds__(256) void zero_out(float* __restrict__ out)
{
  const int idx = blockIdx.x * 256 + threadIdx.x;
  const float4 z4 = {0.f, 0.f, 0.f, 0.f};
  *(float4*)(out + (size_t)idx * 4) = z4;
}

// ============================================================
// Kernel 1: pack W3-like operand into per-wave FRAGMENT order (grid 268):
//   w3p[(os*67 + ks)*2048 + i2*1024 + n*512 + lane*8 + j]
//     = B[o = os*32+n*16+(lane&15)][k = (2ks+i2)*32 + (lane>>4)*8 + j]
// slices (2ks+i2): 0..127 wW3 ; 128..131 wb3 (A=x) ; 132 bW3 (A=h2b) ; 133 zeros.
// ============================================================
__global__ __launch_bounds__(256) void prep_w3(
    const float* __restrict__ wW3, const float* __restrict__ wb3,
    const float* __restrict__ bW3, f16* __restrict__ w3p)
{
  const int idx  = blockIdx.x * 256 + threadIdx.x;   // 0..68607
  const int lane = idx & 63;
  int rest = idx >> 6;
  const int n  = rest & 1;  rest >>= 1;
  const int i2 = rest & 1;  rest >>= 1;              // rest = os*67+ks in [0,268)
  const int ks = rest % 67;
  const int os = rest / 67;

  const int o     = os * 32 + n * 16 + (lane & 15);
  const int slice = ks * 2 + i2;
  const int h0    = (lane >> 4) * 8;

  float v[8];
  if (slice < 133) {
    const float* src;
    if      (slice < 128) src = wW3 + ((size_t)o * 128 + slice) * 32 + h0;
    else if (slice < 132) src = wb3 + (size_t)o * 128 + (slice - 128) * 32 + h0;
    else                  src = bW3 + (size_t)o * 32 + h0;
    float4 a = *(const float4*)src;
    float4 b = *(const float4*)(src + 4);
    v[0]=a.x; v[1]=a.y; v[2]=a.z; v[3]=a.w; v[4]=b.x; v[5]=b.y; v[6]=b.z; v[7]=b.w;
  } else {
#pragma unroll
    for (int j = 0; j < 8; ++j) v[j] = 0.f;
  }
  h8v pk;
#pragma unroll
  for (int j = 0; j < 8; ++j) pk[j] = (f16)v[j];
  *(h8v*)(w3p + ((size_t)rest * 2048 + i2 * 1024 + n * 512 + lane * 8)) = pk;
}

// ============================================================
// Kernel 2: hyper-MLP (thread-per-token, branch-uniform blocks, grid 128)
// + x->f16 cast (coalesced strip per block).
// ============================================================
__global__ __launch_bounds__(256) void hyper_kernel(
    const float* __restrict__ x, const float* __restrict__ z,
    const float* __restrict__ wW1, const float* __restrict__ wb1,
    const float* __restrict__ wg1, const float* __restrict__ wbe1,
    const float* __restrict__ wW2, const float* __restrict__ wb2,
    const float* __restrict__ wg2, const float* __restrict__ wbe2,
    const float* __restrict__ bW1, const float* __restrict__ bb1,
    const float* __restrict__ bg1, const float* __restrict__ bbe1,
    const float* __restrict__ bW2, const float* __restrict__ bb2,
    const float* __restrict__ bg2, const float* __restrict__ bbe2,
    f16* __restrict__ xf, f16* __restrict__ h2w, f16* __restrict__ h2b)
{
  const int tid = threadIdx.x;
  const int bid = blockIdx.x;

  // ---- x -> f16, block-strided, coalesced ----
  {
    const size_t base = (size_t)bid * 16384;
#pragma unroll
    for (int u = 0; u < 16; ++u) {
      const size_t off = base + u * 1024 + tid * 4;
      float4 a = *(const float4*)(x + off);
      h4v p; p[0] = (f16)a.x; p[1] = (f16)a.y; p[2] = (f16)a.z; p[3] = (f16)a.w;
      *(h4v*)(xf + off) = p;
    }
  }

  // ---- hyper MLP, one token-eval per thread ----
  const int br  = bid >> 6;                    // 0 = weight, 1 = bias branch
  const int tok = (bid & 63) * 256 + tid;
  const float* W1  = br ? bW1  : wW1;  const float* b1  = br ? bb1  : wb1;
  const float* g1  = br ? bg1  : wg1;  const float* be1 = br ? bbe1 : wbe1;
  const float* W2  = br ? bW2  : wW2;  const float* b2  = br ? bb2  : wb2;
  const float* g2  = br ? bg2  : wg2;  const float* be2 = br ? bbe2 : wbe2;
  f16* dst = (br ? h2b : h2w) + (size_t)tok * 32;

  const float z0 = z[tok * 3 + 0], z1 = z[tok * 3 + 1], z2 = z[tok * 3 + 2];

  float h1[32];
  float s = 0.f, s2 = 0.f;
#pragma unroll
  for (int j = 0; j < 32; ++j) {
    float v = W1[j * 3] * z0 + W1[j * 3 + 1] * z1 + W1[j * 3 + 2] * z2 + b1[j];
    h1[j] = v; s += v; s2 += v * v;
  }
  float mu  = s * (1.f / 32.f);
  float var = fmaxf(s2 * (1.f / 32.f) - mu * mu, 0.f);
  float rr  = rsqrtf(var + LN_EPS);
#pragma unroll
  for (int j = 0; j < 32; ++j)
    h1[j] = fmaxf((h1[j] - mu) * rr * g1[j] + be1[j], 0.f);

  float h2a[32];
  s = 0.f; s2 = 0.f;
#pragma unroll
  for (int j = 0; j < 32; ++j) {
    float acc = b2[j];
#pragma unroll
    for (int kk = 0; kk < 8; ++kk) {
      float4 w = *(const float4*)&W2[j * 32 + kk * 4];
      acc += w.x * h1[kk * 4] + w.y * h1[kk * 4 + 1]
           + w.z * h1[kk * 4 + 2] + w.w * h1[kk * 4 + 3];
    }
    h2a[j] = acc; s += acc; s2 += acc * acc;
  }
  mu  = s * (1.f / 32.f);
  var = fmaxf(s2 * (1.f / 32.f) - mu * mu, 0.f);
  rr  = rsqrtf(var + LN_EPS);
#pragma unroll
  for (int j8 = 0; j8 < 4; ++j8) {
    h8v pk;
#pragma unroll
    for (int j = 0; j < 8; ++j)
      pk[j] = (f16)fmaxf((h2a[j8*8+j] - mu) * rr * g2[j8*8+j] + be2[j8*8+j], 0.f);
    *(h8v*)(dst + j8 * 8) = pk;
  }
}

// ============================================================
// Kernel 3: U-GEMM. Tile M=64 x N=128, splitK-4 via fp32 atomicAdd.
// grid 1024: tile = bx & 255, kh = bx >> 8 (XCD-grouped quarters).
// 256 thr = 4 waves, one 32-o strip each. Wave tile 64tok x 32o,
// 16 MFMA/iter, DEPTH-3 reg pipeline, barrier-free main loop,
// contiguous 1KB B wave-bursts. Plain launch_bounds(256): let the
// allocator take ~124-150 VGPR (the ",4" hint forced a 64-VGPR spill
// tier in R7/R8). A from LDS dup-pair x. Quarter 0 adds bb3.
// ============================================================
__global__ __launch_bounds__(256) void gemm_kernel(
    const f16* __restrict__ xf, const f16* __restrict__ w3p,
    const f16* __restrict__ h2w, const f16* __restrict__ h2b,
    const float* __restrict__ bb3, float* __restrict__ out)
{
  __shared__ uint32_t xd[64][130];   // (x,x) packed pairs, 33.3 KB

  const int tid   = threadIdx.x;
  const int lane  = tid & 63;
  const int strip = tid >> 6;                  // wave = o-strip
  const int lm    = lane & 15, hc = lane >> 4, hbase = hc * 8;
  const int tile  = blockIdx.x & 255;
  const int kh    = blockIdx.x >> 8;           // K-quarter, XCD-grouped
  const int t0    = tile * 64;
  const int o0    = strip * 32;
  const int ks0   = kh * 17;
  const int n_it  = (kh == 3) ? 16 : 17;

  // ---- contiguous B pointer: 4KB per iter, one 1KB wave-burst per frag ----
  const f16* bp = w3p + (size_t)(strip * 67 + ks0) * 2048 + lane * 8;

#define LOADSET(S) do { \
    S[0][0] = *(const h8v*)(bp); \
    S[0][1] = *(const h8v*)(bp + 512); \
    S[1][0] = *(const h8v*)(bp + 1024); \
    S[1][1] = *(const h8v*)(bp + 1536); \
    bp += 2048; } while (0)

  // issue first three B prefetches before everything else (depth-3)
  h8v b0[2][2], b1[2][2], b2[2][2];
  LOADSET(b0);
  LOADSET(b1);
  LOADSET(b2);

  // ---- per-lane h2 fragments (global, once) ----
  uint32_t h2p[4][4];
#pragma unroll
  for (int m = 0; m < 4; ++m) {
    H8U c; c.v = *(const h8v*)(h2w + (size_t)(t0 + m * 16 + lm) * 32 + hbase);
#pragma unroll
    for (int q = 0; q < 4; ++q) h2p[m][q] = c.u[q];
  }

  float bbv[2];
#pragma unroll
  for (int n = 0; n < 2; ++n)
    bbv[n] = (kh == 0) ? bb3[o0 + n * 16 + lm] : 0.f;

  // ---- build xd: pre-duplicated x pairs (u32 = (x,x)) ----
  {
    const int r = tid >> 2, c0 = (tid & 3) * 32;
    const f16* src = xf + (size_t)(t0 + r) * 128 + c0;
#pragma unroll
    for (int u = 0; u < 4; ++u) {
      H8S hh; hh.v = *(const h8v*)(src + u * 8);
#pragma unroll
      for (int p = 0; p < 4; ++p) {
        uint2 d;
        d.x = (uint32_t)hh.s[p * 2]     * 0x10001u;
        d.y = (uint32_t)hh.s[p * 2 + 1] * 0x10001u;
        *(uint2*)&xd[r][c0 + u * 8 + p * 2] = d;
      }
    }
  }

  __syncthreads();   // xd ready; only barrier in the kernel

  f32x4 acc[4][2];
#pragma unroll
  for (int m = 0; m < 4; ++m)
#pragma unroll
    for (int n = 0; n < 2; ++n) acc[m][n] = (f32x4){0.f, 0.f, 0.f, 0.f};

  auto STEP = [&](h8v (&bs)[2][2], int ks) {
    const int ksg = ks0 + ks;
    h8v af0[4], af1[4];
    if (__builtin_expect(ksg < 64, 1)) {
      // main slices: A = x * h2 (dup-pair ds_read_b64 + packed muls)
#pragma unroll
      for (int m = 0; m < 4; ++m) {
        const uint2 xx = *(const uint2*)&xd[m * 16 + lm][2 * ksg];
        H2U x0, x1; x0.u = xx.x; x1.u = xx.y;
        H8U r0, r1;
#pragma unroll
        for (int q = 0; q < 4; ++q) {
          H2U hq; hq.u = h2p[m][q];
          H2U p0; p0.h = x0.h * hq.h; r0.u[q] = p0.u;
          H2U p1; p1.h = x1.h * hq.h; r1.u[q] = p1.u;
        }
        af0[m] = r0.v; af1[m] = r1.v;
      }
    } else if (ksg < 66) {
      // ext slices (b3 term): A = x directly (global, 2 iters only)
      const int s = (ksg - 64) * 2;
#pragma unroll
      for (int m = 0; m < 4; ++m) {
        const f16* xr = xf + (size_t)(t0 + m * 16 + lm) * 128;
        af0[m] = *(const h8v*)(xr + s * 32 + hbase);
        af1[m] = *(const h8v*)(xr + (s + 1) * 32 + hbase);
      }
    } else {
      // bias slice (A = h2b); i2=1 pairs with zero B
#pragma unroll
      for (int m = 0; m < 4; ++m) {
        af0[m] = *(const h8v*)(h2b + (size_t)(t0 + m * 16 + lm) * 32 + hbase);
        af1[m] = af0[m];
      }
    }
    __builtin_amdgcn_s_setprio(1);
#pragma unroll
    for (int n = 0; n < 2; ++n)
#pragma unroll
      for (int m = 0; m < 4; ++m)
        acc[m][n] = __builtin_amdgcn_mfma_f32_16x16x32_f16(af0[m], bs[0][n], acc[m][n], 0, 0, 0);
#pragma unroll
    for (int n = 0; n < 2; ++n)
#pragma unroll
      for (int m = 0; m < 4; ++m)
        acc[m][n] = __builtin_amdgcn_mfma_f32_16x16x32_f16(af1[m], bs[1][n], acc[m][n], 0, 0, 0);
    __builtin_amdgcn_s_setprio(0);
  };

  int ks = 0;
#pragma unroll 1
  while (ks + 3 <= n_it) {
    STEP(b0, ks);     if (ks + 3 < n_it) LOADSET(b0);
    STEP(b1, ks + 1); if (ks + 4 < n_it) LOADSET(b1);
    STEP(b2, ks + 2); if (ks + 5 < n_it) LOADSET(b2);
    ks += 3;
  }
  if (ks < n_it) { STEP(b0, ks); ++ks; }
  if (ks < n_it) { STEP(b1, ks); ++ks; }
#undef LOADSET

  // ---- epilogue: C/D col=lane&15, row=(lane>>4)*4+reg ; atomic splitK sum ----
#pragma unroll
  for (int m = 0; m < 4; ++m) {
#pragma unroll
    for (int n = 0; n < 2; ++n) {
      const int gc = o0 + n * 16 + lm;
#pragma unroll
      for (int r_ = 0; r_ < 4; ++r_) {
        const int row = t0 + m * 16 + hc * 4 + r_;
        atomicAdd(&out[(size_t)row * 128 + gc], acc[m][n][r_] + bbv[n]);
      }
    }
  }
}

// ============================================================
extern "C" void kernel_launch(void* const* d_in, const int* in_sizes, int n_in,
                              void* d_out, int out_size, void* d_ws, size_t ws_size,
                              hipStream_t stream)
{
  const float* x    = (const float*)d_in[0];
  const float* z    = (const float*)d_in[1];
  const float* wW1  = (const float*)d_in[2];
  const float* wb1  = (const float*)d_in[3];
  const float* wg1  = (const float*)d_in[4];
  const float* wbe1 = (const float*)d_in[5];
  const float* wW2  = (const float*)d_in[6];
  const float* wb2  = (const float*)d_in[7];
  const float* wg2  = (const float*)d_in[8];
  const float* wbe2 = (const float*)d_in[9];
  const float* wW3  = (const float*)d_in[10];
  const float* wb3  = (const float*)d_in[11];
  const float* bW1  = (const float*)d_in[12];
  const float* bb1  = (const float*)d_in[13];
  const float* bg1  = (const float*)d_in[14];
  const float* bbe1 = (const float*)d_in[15];
  const float* bW2  = (const float*)d_in[16];
  const float* bb2  = (const float*)d_in[17];
  const float* bg2  = (const float*)d_in[18];
  const float* bbe2 = (const float*)d_in[19];
  const float* bW3  = (const float*)d_in[20];
  const float* bb3  = (const float*)d_in[21];

  uint8_t* ws = (uint8_t*)d_ws;
  f16* w3p = (f16*)ws;                         // 1,097,728 B
  f16* xf  = (f16*)(ws + 1097728);             // 4,194,304 B
  f16* h2w = (f16*)(ws + 1097728 + 4194304);   // 1,048,576 B
  f16* h2b = (f16*)(ws + 1097728 + 4194304 + 1048576);
  float* outf = (float*)d_out;

  hipLaunchKernelGGL(zero_out, dim3(2048), dim3(256), 0, stream, outf);
  hipLaunchKernelGGL(prep_w3, dim3(268), dim3(256), 0, stream, wW3, wb3, bW3, w3p);
  hipLaunchKernelGGL(hyper_kernel, dim3(128), dim3(256), 0, stream,
                     x, z,
                     wW1, wb1, wg1, wbe1, wW2, wb2, wg2, wbe2,
                     bW1, bb1, bg1, bbe1, bW2, bb2, bg2, bbe2,
                     xf, h2w, h2b);
  hipLaunchKernelGGL(gemm_kernel, dim3(1024), dim3(256), 0, stream,
                     xf, w3p, h2w, h2b, bb3, outf);
}

// Round 12
// 66.926 us; speedup vs baseline: 1.1359x; 1.1359x over previous
//
#include <hip/hip_runtime.h>
#include <hip/hip_fp16.h>
#include <stdint.h>

// ---------------- problem constants ----------------
#define T_DIM   16384       // S*B tokens
#define LN_EPS  1e-5f

typedef _Float16 f16;
typedef __attribute__((ext_vector_type(2))) _Float16 h2v;
typedef __attribute__((ext_vector_type(4))) _Float16 h4v;
typedef __attribute__((ext_vector_type(8))) _Float16 h8v;
typedef __attribute__((ext_vector_type(4))) float    f32x4;

union H2U { uint32_t u; h2v h; };
union H8U { uint32_t u[4]; h8v v; };

__device__ __forceinline__ void g2l16(const f16* g, f16* l) {
  __builtin_amdgcn_global_load_lds(
      (const __attribute__((address_space(1))) uint32_t*)g,
      (__attribute__((address_space(3))) uint32_t*)l, 16, 0, 0);
}

// ============================================================
// Kernel 1: blocks 0..267 pack W3 into per-wave FRAGMENT order;
// blocks 268..2315 zero d_out (atomicAdd base).
//   w3p[(os*67 + ks)*2048 + f*512 + lane*8 + j]   (f = i2*2 + n)
//     = B[o = os*32+n*16+(lane&15)][k = (2ks+i2)*32 + (lane>>4)*8 + j]
// slices (2ks+i2): 0..127 wW3 ; 128..131 wb3 (A=x) ; 132 bW3 (A=h2b) ; 133 zeros.
// ============================================================
__global__ __launch_bounds__(256) void prep_w3z(
    const float* __restrict__ wW3, const float* __restrict__ wb3,
    const float* __restrict__ bW3, f16* __restrict__ w3p,
    float* __restrict__ outz)
{
  const int bid = blockIdx.x;
  if (bid >= 268) {
    const int idx = (bid - 268) * 256 + threadIdx.x;   // 0..524287
    const float4 z4 = {0.f, 0.f, 0.f, 0.f};
    *(float4*)(outz + (size_t)idx * 4) = z4;
    return;
  }

  const int idx  = bid * 256 + threadIdx.x;            // 0..68607
  const int lane = idx & 63;
  int rest = idx >> 6;
  const int n  = rest & 1;  rest >>= 1;
  const int i2 = rest & 1;  rest >>= 1;                // rest = os*67+ks in [0,268)
  const int ks = rest % 67;
  const int os = rest / 67;

  const int o     = os * 32 + n * 16 + (lane & 15);
  const int slice = ks * 2 + i2;
  const int h0    = (lane >> 4) * 8;

  float v[8];
  if (slice < 133) {
    const float* src;
    if      (slice < 128) src = wW3 + ((size_t)o * 128 + slice) * 32 + h0;
    else if (slice < 132) src = wb3 + (size_t)o * 128 + (slice - 128) * 32 + h0;
    else                  src = bW3 + (size_t)o * 32 + h0;
    float4 a = *(const float4*)src;
    float4 b = *(const float4*)(src + 4);
    v[0]=a.x; v[1]=a.y; v[2]=a.z; v[3]=a.w; v[4]=b.x; v[5]=b.y; v[6]=b.z; v[7]=b.w;
  } else {
#pragma unroll
    for (int j = 0; j < 8; ++j) v[j] = 0.f;
  }
  h8v pk;
#pragma unroll
  for (int j = 0; j < 8; ++j) pk[j] = (f16)v[j];
  *(h8v*)(w3p + ((size_t)rest * 2048 + (i2 * 2 + n) * 512 + lane * 8)) = pk;
}

// ============================================================
// Kernel 2: hyper-MLP (thread-per-token, branch-uniform blocks, grid 128)
// + x->f16 cast (coalesced strip per block).
// ============================================================
__global__ __launch_bounds__(256) void hyper_kernel(
    const float* __restrict__ x, const float* __restrict__ z,
    const float* __restrict__ wW1, const float* __restrict__ wb1,
    const float* __restrict__ wg1, const float* __restrict__ wbe1,
    const float* __restrict__ wW2, const float* __restrict__ wb2,
    const float* __restrict__ wg2, const float* __restrict__ wbe2,
    const float* __restrict__ bW1, const float* __restrict__ bb1,
    const float* __restrict__ bg1, const float* __restrict__ bbe1,
    const float* __restrict__ bW2, const float* __restrict__ bb2,
    const float* __restrict__ bg2, const float* __restrict__ bbe2,
    f16* __restrict__ xf, f16* __restrict__ h2w, f16* __restrict__ h2b)
{
  const int tid = threadIdx.x;
  const int bid = blockIdx.x;

  {
    const size_t base = (size_t)bid * 16384;
#pragma unroll
    for (int u = 0; u < 16; ++u) {
      const size_t off = base + u * 1024 + tid * 4;
      float4 a = *(const float4*)(x + off);
      h4v p; p[0] = (f16)a.x; p[1] = (f16)a.y; p[2] = (f16)a.z; p[3] = (f16)a.w;
      *(h4v*)(xf + off) = p;
    }
  }

  const int br  = bid >> 6;                    // 0 = weight, 1 = bias branch
  const int tok = (bid & 63) * 256 + tid;
  const float* W1  = br ? bW1  : wW1;  const float* b1  = br ? bb1  : wb1;
  const float* g1  = br ? bg1  : wg1;  const float* be1 = br ? bbe1 : wbe1;
  const float* W2  = br ? bW2  : wW2;  const float* b2  = br ? bb2  : wb2;
  const float* g2  = br ? bg2  : wg2;  const float* be2 = br ? bbe2 : wbe2;
  f16* dst = (br ? h2b : h2w) + (size_t)tok * 32;

  const float z0 = z[tok * 3 + 0], z1 = z[tok * 3 + 1], z2 = z[tok * 3 + 2];

  float h1[32];
  float s = 0.f, s2 = 0.f;
#pragma unroll
  for (int j = 0; j < 32; ++j) {
    float v = W1[j * 3] * z0 + W1[j * 3 + 1] * z1 + W1[j * 3 + 2] * z2 + b1[j];
    h1[j] = v; s += v; s2 += v * v;
  }
  float mu  = s * (1.f / 32.f);
  float var = fmaxf(s2 * (1.f / 32.f) - mu * mu, 0.f);
  float rr  = rsqrtf(var + LN_EPS);
#pragma unroll
  for (int j = 0; j < 32; ++j)
    h1[j] = fmaxf((h1[j] - mu) * rr * g1[j] + be1[j], 0.f);

  float h2a[32];
  s = 0.f; s2 = 0.f;
#pragma unroll
  for (int j = 0; j < 32; ++j) {
    float acc = b2[j];
#pragma unroll
    for (int kk = 0; kk < 8; ++kk) {
      float4 w = *(const float4*)&W2[j * 32 + kk * 4];
      acc += w.x * h1[kk * 4] + w.y * h1[kk * 4 + 1]
           + w.z * h1[kk * 4 + 2] + w.w * h1[kk * 4 + 3];
    }
    h2a[j] = acc; s += acc; s2 += acc * acc;
  }
  mu  = s * (1.f / 32.f);
  var = fmaxf(s2 * (1.f / 32.f) - mu * mu, 0.f);
  rr  = rsqrtf(var + LN_EPS);
#pragma unroll
  for (int j8 = 0; j8 < 4; ++j8) {
    h8v pk;
#pragma unroll
    for (int j = 0; j < 8; ++j)
      pk[j] = (f16)fmaxf((h2a[j8*8+j] - mu) * rr * g2[j8*8+j] + be2[j8*8+j], 0.f);
    *(h8v*)(dst + j8 * 8) = pk;
  }
}

// ============================================================
// Kernel 3: U-GEMM. Tile M=64 x N=128, splitK-2 via fp32 atomicAdd.
// grid 512: tile = bx & 255, kh = bx >> 8 (XCD-grouped halves).
// 256 thr = 4 waves, one 32-o strip each; ~50KB LDS -> 3 blocks/CU.
// B pipelining via global_load_lds into PER-WAVE PRIVATE double buffers
// (no cross-wave barrier in the loop, each wave self-paced by its own
// vmcnt): WAIT = asm s_waitcnt vmcnt(4) + sched_barrier(0) (rule-#18
// fence). No VGPR-destination async loads -> no copy hazard (R11 NaN).
// WAR on buffer reuse safe: lgkmcnt(0) before MFMAs drains ds_reads,
// re-ISSUE pinned after them by sched_barrier(0). Half 0 adds bb3.
// ============================================================
__global__ __launch_bounds__(256) void gemm_kernel(
    const f16* __restrict__ xf, const f16* __restrict__ w3p,
    const f16* __restrict__ h2w, const f16* __restrict__ h2b,
    const float* __restrict__ bb3, float* __restrict__ out)
{
  __shared__ __align__(16) f16 xs[64][136];        // x tile f16, 17.4 KB
  __shared__ __align__(16) f16 bsm[2][4][4][512];  // [buf][wave][frag][512], 32 KB

  const int tid   = threadIdx.x;
  const int lane  = tid & 63;
  const int strip = tid >> 6;                  // wave = o-strip
  const int lm    = lane & 15, hc = lane >> 4, hbase = hc * 8;
  const int tile  = blockIdx.x & 255;
  const int kh    = blockIdx.x >> 8;           // 0 or 1 (XCD-grouped)
  const int t0    = tile * 64;
  const int o0    = strip * 32;
  const int ks0   = kh * 34;
  const int n_main = kh ? 30 : 34;             // kh1: ks 34..63 main, 64..66 epilogue

  // per-wave global source base (per-lane address; LDS dest is uniform+lane*16)
  const f16* gb = w3p + (size_t)(strip * 67 + ks0) * 2048 + lane * 8;

#define ISSUE(BUF, KS) do { \
    const f16* gs_ = gb + (size_t)(KS) * 2048; \
    g2l16(gs_,        &bsm[BUF][strip][0][0]); \
    g2l16(gs_ + 512,  &bsm[BUF][strip][1][0]); \
    g2l16(gs_ + 1024, &bsm[BUF][strip][2][0]); \
    g2l16(gs_ + 1536, &bsm[BUF][strip][3][0]); } while (0)

#define WAITN(N) do { \
    asm volatile("s_waitcnt vmcnt(" #N ")" ::: "memory"); \
    __builtin_amdgcn_sched_barrier(0); } while (0)

  // ---- per-lane h2 fragments (global, once) ----
  uint32_t h2p[4][4];
#pragma unroll
  for (int m = 0; m < 4; ++m) {
    H8U c; c.v = *(const h8v*)(h2w + (size_t)(t0 + m * 16 + lm) * 32 + hbase);
#pragma unroll
    for (int q = 0; q < 4; ++q) h2p[m][q] = c.u[q];
  }

  float bbv[2];
#pragma unroll
  for (int n = 0; n < 2; ++n)
    bbv[n] = (kh == 0) ? bb3[o0 + n * 16 + lm] : 0.f;

  // ---- stage x tile: f16 global -> LDS ----
  {
    const int r = tid >> 2, c0 = (tid & 3) * 32;
    const f16* src = xf + (size_t)(t0 + r) * 128 + c0;
#pragma unroll
    for (int u = 0; u < 4; ++u)
      *(h8v*)&xs[r][c0 + u * 8] = *(const h8v*)(src + u * 8);
  }

  // ---- prologue B DMA: buffers 0,1 (drained by syncthreads, data in LDS) ----
  ISSUE(0, 0);
  ISSUE(1, 1);

  __syncthreads();   // xs + prologue DMAs complete; only block barrier

  f32x4 acc[4][2];
#pragma unroll
  for (int m = 0; m < 4; ++m)
#pragma unroll
    for (int n = 0; n < 2; ++n) acc[m][n] = (f32x4){0.f, 0.f, 0.f, 0.f};

  auto STEP = [&](int k) {
    const int buf = k & 1;
    const int ksg = ks0 + k;
    // B fragments from private LDS (lane*8 f16 = lane*16B)
    h8v b0 = *(const h8v*)&bsm[buf][strip][0][lane * 8];
    h8v b1 = *(const h8v*)&bsm[buf][strip][1][lane * 8];
    h8v b2 = *(const h8v*)&bsm[buf][strip][2][lane * 8];
    h8v b3 = *(const h8v*)&bsm[buf][strip][3][lane * 8];
    // A fragments: x pair * h2
    h8v af0[4], af1[4];
#pragma unroll
    for (int m = 0; m < 4; ++m) {
      const uint32_t xp = *(const uint32_t*)&xs[m * 16 + lm][2 * ksg];
      H2U x0, x1;
      x0.u = (xp & 0xffffu) | (xp << 16);
      x1.u = (xp >> 16) | (xp & 0xffff0000u);
      H8U r0, r1;
#pragma unroll
      for (int q = 0; q < 4; ++q) {
        H2U hq; hq.u = h2p[m][q];
        H2U p0; p0.h = x0.h * hq.h; r0.u[q] = p0.u;
        H2U p1; p1.h = x1.h * hq.h; r1.u[q] = p1.u;
      }
      af0[m] = r0.v; af1[m] = r1.v;
    }
    __builtin_amdgcn_s_setprio(1);
#pragma unroll
    for (int m = 0; m < 4; ++m)
      acc[m][0] = __builtin_amdgcn_mfma_f32_16x16x32_f16(af0[m], b0, acc[m][0], 0, 0, 0);
#pragma unroll
    for (int m = 0; m < 4; ++m)
      acc[m][1] = __builtin_amdgcn_mfma_f32_16x16x32_f16(af0[m], b1, acc[m][1], 0, 0, 0);
#pragma unroll
    for (int m = 0; m < 4; ++m)
      acc[m][0] = __builtin_amdgcn_mfma_f32_16x16x32_f16(af1[m], b2, acc[m][0], 0, 0, 0);
#pragma unroll
    for (int m = 0; m < 4; ++m)
      acc[m][1] = __builtin_amdgcn_mfma_f32_16x16x32_f16(af1[m], b3, acc[m][1], 0, 0, 0);
    __builtin_amdgcn_s_setprio(0);
  };

  int k = 0;
#pragma unroll 1
  for (; k < n_main - 1; ++k) {
    WAITN(4);                          // oldest set (buf k&1) landed
    STEP(k);
    __builtin_amdgcn_sched_barrier(0); // pin re-ISSUE after the ds_reads/MFMAs
    if (k + 2 < n_main) ISSUE(k & 1, k + 2);
  }
  WAITN(0);
  STEP(n_main - 1);

#undef ISSUE
#undef WAITN

  // ---- kh==1 epilogue: ext slices (ks 64,65: A=x) and bias slice (ks 66) ----
  if (kh == 1) {
    const f16* bpe = w3p + (size_t)(strip * 67 + 64) * 2048 + lane * 8;
#pragma unroll 1
    for (int e = 0; e < 2; ++e) {
      h8v bs00 = *(const h8v*)(bpe);
      h8v bs01 = *(const h8v*)(bpe + 512);
      h8v bs10 = *(const h8v*)(bpe + 1024);
      h8v bs11 = *(const h8v*)(bpe + 1536);
      bpe += 2048;
      const int s = e * 2;
      h8v af0[4], af1[4];
#pragma unroll
      for (int m = 0; m < 4; ++m) {
        af0[m] = *(const h8v*)&xs[m * 16 + lm][s * 32 + hbase];
        af1[m] = *(const h8v*)&xs[m * 16 + lm][(s + 1) * 32 + hbase];
      }
#pragma unroll
      for (int m = 0; m < 4; ++m) {
        acc[m][0] = __builtin_amdgcn_mfma_f32_16x16x32_f16(af0[m], bs00, acc[m][0], 0, 0, 0);
        acc[m][1] = __builtin_amdgcn_mfma_f32_16x16x32_f16(af0[m], bs01, acc[m][1], 0, 0, 0);
        acc[m][0] = __builtin_amdgcn_mfma_f32_16x16x32_f16(af1[m], bs10, acc[m][0], 0, 0, 0);
        acc[m][1] = __builtin_amdgcn_mfma_f32_16x16x32_f16(af1[m], bs11, acc[m][1], 0, 0, 0);
      }
    }
    {   // bias slice ks 66 (i2=1 half is zeros by construction)
      h8v bs00 = *(const h8v*)(bpe);
      h8v bs01 = *(const h8v*)(bpe + 512);
      h8v af[4];
#pragma unroll
      for (int m = 0; m < 4; ++m)
        af[m] = *(const h8v*)(h2b + (size_t)(t0 + m * 16 + lm) * 32 + hbase);
#pragma unroll
      for (int m = 0; m < 4; ++m) {
        acc[m][0] = __builtin_amdgcn_mfma_f32_16x16x32_f16(af[m], bs00, acc[m][0], 0, 0, 0);
        acc[m][1] = __builtin_amdgcn_mfma_f32_16x16x32_f16(af[m], bs01, acc[m][1], 0, 0, 0);
      }
    }
  }

  // ---- epilogue: C/D col=lane&15, row=(lane>>4)*4+reg ; atomic splitK sum ----
#pragma unroll
  for (int m = 0; m < 4; ++m) {
#pragma unroll
    for (int n = 0; n < 2; ++n) {
      const int gc = o0 + n * 16 + lm;
#pragma unroll
      for (int r_ = 0; r_ < 4; ++r_) {
        const int row = t0 + m * 16 + hc * 4 + r_;
        atomicAdd(&out[(size_t)row * 128 + gc], acc[m][n][r_] + bbv[n]);
      }
    }
  }
}

// ============================================================
extern "C" void kernel_launch(void* const* d_in, const int* in_sizes, int n_in,
                              void* d_out, int out_size, void* d_ws, size_t ws_size,
                              hipStream_t stream)
{
  const float* x    = (const float*)d_in[0];
  const float* z    = (const float*)d_in[1];
  const float* wW1  = (const float*)d_in[2];
  const float* wb1  = (const float*)d_in[3];
  const float* wg1  = (const float*)d_in[4];
  const float* wbe1 = (const float*)d_in[5];
  const float* wW2  = (const float*)d_in[6];
  const float* wb2  = (const float*)d_in[7];
  const float* wg2  = (const float*)d_in[8];
  const float* wbe2 = (const float*)d_in[9];
  const float* wW3  = (const float*)d_in[10];
  const float* wb3  = (const float*)d_in[11];
  const float* bW1  = (const float*)d_in[12];
  const float* bb1  = (const float*)d_in[13];
  const float* bg1  = (const float*)d_in[14];
  const float* bbe1 = (const float*)d_in[15];
  const float* bW2  = (const float*)d_in[16];
  const float* bb2  = (const float*)d_in[17];
  const float* bg2  = (const float*)d_in[18];
  const float* bbe2 = (const float*)d_in[19];
  const float* bW3  = (const float*)d_in[20];
  const float* bb3  = (const float*)d_in[21];

  uint8_t* ws = (uint8_t*)d_ws;
  f16* w3p = (f16*)ws;                         // 1,097,728 B
  f16* xf  = (f16*)(ws + 1097728);             // 4,194,304 B
  f16* h2w = (f16*)(ws + 1097728 + 4194304);   // 1,048,576 B
  f16* h2b = (f16*)(ws + 1097728 + 4194304 + 1048576);
  float* outf = (float*)d_out;

  hipLaunchKernelGGL(prep_w3z, dim3(2316), dim3(256), 0, stream,
                     wW3, wb3, bW3, w3p, outf);
  hipLaunchKernelGGL(hyper_kernel, dim3(128), dim3(256), 0, stream,
                     x, z,
                     wW1, wb1, wg1, wbe1, wW2, wb2, wg2, wbe2,
                     bW1, bb1, bg1, bbe1, bW2, bb2, bg2, bbe2,
                     xf, h2w, h2b);
  hipLaunchKernelGGL(gemm_kernel, dim3(512), dim3(256), 0, stream,
                     xf, w3p, h2w, h2b, bb3, outf);
}